// Round 1
// baseline (323.133 us; speedup 1.0000x reference)
//
#include <hip/hip_runtime.h>

typedef unsigned short u16;
typedef unsigned int u32;
typedef short bf16x8 __attribute__((ext_vector_type(8)));
typedef float f32x4 __attribute__((ext_vector_type(4)));

#define BM 128
#define BN 128

// ---------- helpers ----------
__device__ __forceinline__ u16 f2bf(float f) {
    u32 u = __float_as_uint(f);
    u32 r = (u + 0x7fffu + ((u >> 16) & 1u)) >> 16;   // RNE
    return (u16)r;
}

__device__ __forceinline__ void unpack8(uint4 u, float* f) {
    f[0] = __uint_as_float(u.x << 16); f[1] = __uint_as_float(u.x & 0xffff0000u);
    f[2] = __uint_as_float(u.y << 16); f[3] = __uint_as_float(u.y & 0xffff0000u);
    f[4] = __uint_as_float(u.z << 16); f[5] = __uint_as_float(u.z & 0xffff0000u);
    f[6] = __uint_as_float(u.w << 16); f[7] = __uint_as_float(u.w & 0xffff0000u);
}

// async 16B/lane global->LDS (dest = wave-uniform base + lane*16)
__device__ __forceinline__ void gld_lds16(const void* g, void* s) {
    __builtin_amdgcn_global_load_lds(
        (__attribute__((address_space(1))) void*)(g),
        (__attribute__((address_space(3))) void*)(s),
        16, 0, 0);
}

// ---------- cast kernels ----------
__global__ void cast_x_kernel(const float* __restrict__ s, u16* __restrict__ d, int n) {
    int i = (blockIdx.x * blockDim.x + threadIdx.x) * 4;
    if (i < n) {
        float4 v = *(const float4*)(s + i);
        ushort4 o;
        o.x = f2bf(v.x); o.y = f2bf(v.y); o.z = f2bf(v.z); o.w = f2bf(v.w);
        *(ushort4*)(d + i) = o;
    }
}

__global__ void cast_w_kernel(const float* __restrict__ wq, const float* __restrict__ wk,
                              const float* __restrict__ wv, const float* __restrict__ wfc,
                              u16* __restrict__ wqkv, u16* __restrict__ wfcb) {
    int y = blockIdx.y;
    const float* s = (y == 0) ? wq : (y == 1) ? wk : (y == 2) ? wv : wfc;
    u16* d = (y < 3) ? (wqkv + (size_t)y * (1u << 20)) : wfcb;
    int i = (blockIdx.x * blockDim.x + threadIdx.x) * 4;
    float4 v = *(const float4*)(s + i);
    ushort4 o;
    o.x = f2bf(v.x); o.y = f2bf(v.y); o.z = f2bf(v.z); o.w = f2bf(v.w);
    *(ushort4*)(d + i) = o;
}

// ---------- bf16 GEMM: C[M,N] = A[M,K] * B[N,K]^T ----------
// 128x128 tile, BK=64, 256 threads (4 waves, 2x2), 16x16x32 MFMA, 4x4 acc/wave.
// LDS chunks XOR-swizzled (phys_chunk = logical_chunk ^ (row&7)) via the
// *global* source address of global_load_lds, so b128 frag reads hit the
// 8-dword/bank floor instead of 16-way conflicts.
template <int STOREF32>
__global__ __launch_bounds__(256, 2)
void gemm_bt(const u16* __restrict__ A, const u16* __restrict__ B,
             void* __restrict__ C, int M, int N, int K) {
    __shared__ __align__(16) u16 As[BM * 64];
    __shared__ __align__(16) u16 Bs[BN * 64];

    const int tid  = threadIdx.x;
    const int lane = tid & 63;
    const int wave = tid >> 6;
    const int wm = wave >> 1, wn = wave & 1;
    const int bm = blockIdx.y * BM;
    const int bn = blockIdx.x * BN;

    const int srow   = lane >> 3;            // row within 8-row staging group
    const int schunk = (lane & 7) ^ srow;    // xor-swizzled source chunk

    f32x4 acc[4][4];
#pragma unroll
    for (int i = 0; i < 4; ++i)
#pragma unroll
        for (int j = 0; j < 4; ++j) acc[i][j] = (f32x4){0.f, 0.f, 0.f, 0.f};

    const int nkt = K >> 6;
    for (int kt = 0; kt < nkt; ++kt) {
        const int k0 = kt << 6;
        __syncthreads();   // prior compute done reading LDS
#pragma unroll
        for (int j = 0; j < 4; ++j) {
            const int r = wave * 32 + j * 8;
            gld_lds16(A + (size_t)(bm + r + srow) * K + k0 + schunk * 8, &As[r * 64]);
            gld_lds16(B + (size_t)(bn + r + srow) * K + k0 + schunk * 8, &Bs[r * 64]);
        }
        __syncthreads();   // compiler drains vmcnt before barrier
#pragma unroll
        for (int kk = 0; kk < 2; ++kk) {
            const int c = kk * 4 + (lane >> 4);
            bf16x8 af[4], bfr[4];
#pragma unroll
            for (int i = 0; i < 4; ++i) {
                int m = wm * 64 + i * 16 + (lane & 15);
                af[i] = *(const bf16x8*)&As[m * 64 + ((c ^ (m & 7)) << 3)];
            }
#pragma unroll
            for (int j = 0; j < 4; ++j) {
                int n = wn * 64 + j * 16 + (lane & 15);
                bfr[j] = *(const bf16x8*)&Bs[n * 64 + ((c ^ (n & 7)) << 3)];
            }
#pragma unroll
            for (int i = 0; i < 4; ++i)
#pragma unroll
                for (int j = 0; j < 4; ++j)
                    acc[i][j] = __builtin_amdgcn_mfma_f32_16x16x32_bf16(
                        af[i], bfr[j], acc[i][j], 0, 0, 0);
        }
    }

    // epilogue: D layout col=lane&15, row=(lane>>4)*4+reg
    const int cr = (lane >> 4) * 4;
    const int cc = lane & 15;
#pragma unroll
    for (int i = 0; i < 4; ++i) {
#pragma unroll
        for (int j = 0; j < 4; ++j) {
            const int row0 = bm + wm * 64 + i * 16 + cr;
            const int col  = bn + wn * 64 + j * 16 + cc;
#pragma unroll
            for (int r = 0; r < 4; ++r) {
                float v = acc[i][j][r];
                size_t idx = (size_t)(row0 + r) * N + col;
                if (STOREF32) ((float*)C)[idx] = v;
                else          ((u16*)C)[idx]   = f2bf(v);
            }
        }
    }
}

// ---------- per-token attention: 1 wave = 1 token ----------
// QKV row m: [q(1024) | k(1024) | v(1024)] bf16. 16 heads x 64 dim.
// scores 16x16 over heads axis, softmax over t, O = P @ V -> bf16 [m,1024].
__global__ __launch_bounds__(256)
void attn_kernel(const u16* __restrict__ QKV, u16* __restrict__ O) {
    __shared__ __align__(16) u16 sq[4][3][16 * 72];   // rows padded 64->72
    __shared__ float sp[4][16 * 20];                  // P rows padded 16->20

    const int lane = threadIdx.x & 63;
    const int wave = threadIdx.x >> 6;
    const size_t m = (size_t)blockIdx.x * 4 + wave;
    const u16* base = QKV + m * 3072;

    // stage 6KB/token: 384 16B chunks, 6 per lane, padded LDS layout
#pragma unroll
    for (int c6 = 0; c6 < 6; ++c6) {
        int chunk = c6 * 64 + lane;          // 0..383
        int mat = chunk >> 7;
        int cc  = chunk & 127;
        int row = cc >> 3, pch = cc & 7;
        *(uint4*)&sq[wave][mat][row * 72 + pch * 8] = *(const uint4*)(base + chunk * 8);
    }
    __syncthreads();

    // scores: lane (h = lane&15, g = lane>>4) computes s[h][g*4 .. g*4+3]
    const int h = lane & 15, g = lane >> 4;
    float s[4] = {0.f, 0.f, 0.f, 0.f};
#pragma unroll
    for (int c = 0; c < 8; ++c) {
        uint4 qc = *(const uint4*)&sq[wave][0][h * 72 + c * 8];
        float qf[8]; unpack8(qc, qf);
#pragma unroll
        for (int t4 = 0; t4 < 4; ++t4) {
            int t = g * 4 + t4;
            uint4 kc = *(const uint4*)&sq[wave][1][t * 72 + c * 8];
            float kf[8]; unpack8(kc, kf);
#pragma unroll
            for (int e = 0; e < 8; ++e) s[t4] = fmaf(qf[e], kf[e], s[t4]);
        }
    }
#pragma unroll
    for (int t4 = 0; t4 < 4; ++t4) s[t4] *= 0.125f;   // 1/sqrt(64)

    // softmax over t (row h spread across 4 g-groups: lanes h, h+16, h+32, h+48)
    float mx = fmaxf(fmaxf(s[0], s[1]), fmaxf(s[2], s[3]));
    mx = fmaxf(mx, __shfl_xor(mx, 16));
    mx = fmaxf(mx, __shfl_xor(mx, 32));
    float e[4], sum = 0.f;
#pragma unroll
    for (int t4 = 0; t4 < 4; ++t4) { e[t4] = __expf(s[t4] - mx); sum += e[t4]; }
    sum += __shfl_xor(sum, 16);
    sum += __shfl_xor(sum, 32);
    const float inv = 1.f / sum;
#pragma unroll
    for (int t4 = 0; t4 < 4; ++t4) sp[wave][h * 20 + g * 4 + t4] = e[t4] * inv;
    __syncthreads();

    // PV: lane (h2 = lane&15, dc = lane>>4) computes o[h2][dc*16 .. +15]
    const int h2 = h, dc = g;
    float o[16];
#pragma unroll
    for (int e2 = 0; e2 < 16; ++e2) o[e2] = 0.f;
#pragma unroll
    for (int t = 0; t < 16; ++t) {
        float pv = sp[wave][h2 * 20 + t];
        uint4 v0 = *(const uint4*)&sq[wave][2][t * 72 + dc * 16];
        uint4 v1 = *(const uint4*)&sq[wave][2][t * 72 + dc * 16 + 8];
        float vf[16]; unpack8(v0, vf); unpack8(v1, vf + 8);
#pragma unroll
        for (int e2 = 0; e2 < 16; ++e2) o[e2] = fmaf(pv, vf[e2], o[e2]);
    }
    u16 ob[16];
#pragma unroll
    for (int e2 = 0; e2 < 16; ++e2) ob[e2] = f2bf(o[e2]);
    uint4* dst = (uint4*)(O + m * 1024 + h2 * 64 + dc * 16);
    dst[0] = ((uint4*)ob)[0];
    dst[1] = ((uint4*)ob)[1];
}

// ---------- launch ----------
extern "C" void kernel_launch(void* const* d_in, const int* in_sizes, int n_in,
                              void* d_out, int out_size, void* d_ws, size_t ws_size,
                              hipStream_t stream) {
    const float* x   = (const float*)d_in[0];
    const float* Wq  = (const float*)d_in[1];
    const float* Wk  = (const float*)d_in[2];
    const float* Wv  = (const float*)d_in[3];
    const float* Wfc = (const float*)d_in[4];
    float* out = (float*)d_out;

    // B=4, S=4096, DM=1024 -> M=16384, K=1024, Nqkv=3072
    const int M = 16384, K = 1024, NQKV = 3072, N2 = 1024;

    char* ws = (char*)d_ws;
    u16* xb    = (u16*)ws;                                  // 33,554,432 B (also O later)
    u16* wqkvb = (u16*)(ws + 33554432);                     //  6,291,456 B
    u16* wfcb  = (u16*)(ws + 33554432 + 6291456);           //  2,097,152 B
    u16* qkv   = (u16*)(ws + 33554432 + 6291456 + 2097152); // 100,663,296 B

    cast_x_kernel<<<16384, 256, 0, stream>>>(x, xb, M * K);
    cast_w_kernel<<<dim3(1024, 4), 256, 0, stream>>>(Wq, Wk, Wv, Wfc, wqkvb, wfcb);

    gemm_bt<0><<<dim3(NQKV / BN, M / BM), 256, 0, stream>>>(xb, wqkvb, qkv, M, NQKV, K);

    u16* Ob = xb;   // alias: GEMM1 was the last reader of xb
    attn_kernel<<<M / 4, 256, 0, stream>>>(qkv, Ob);

    gemm_bt<1><<<dim3(N2 / BN, M / BM), 256, 0, stream>>>(Ob, wfcb, out, M, N2, K);
}